// Round 1
// baseline (3674.282 us; speedup 1.0000x reference)
//
#include <hip/hip_runtime.h>

#define B_  4096
#define T_  2048
#define H1_ 32
#define H2_ 16

// sigmoid(x) = 1/(1+e^-x); tanh(x) = 1 - 2/(1+e^{2x})  (saturates cleanly, no NaN)

__global__ __launch_bounds__(64) void lstm_deep_kernel(
    const float* __restrict__ x,
    const float* __restrict__ W_ih1,
    const float* __restrict__ W_hh1,
    const float* __restrict__ b_ih1,
    const float* __restrict__ b_hh1,
    const float* __restrict__ W_ih2,
    const float* __restrict__ W_hh2,
    const float* __restrict__ b_ih2,
    const float* __restrict__ b_hh2,
    const float* __restrict__ W_out,
    const float* __restrict__ b_out,
    float* __restrict__ out)
{
    const int lane = threadIdx.x;   // 0..63, single wave per block
    const int row  = blockIdx.x;    // batch row

    __shared__ __align__(16) float sh_h1[H1_];
    __shared__ __align__(16) float sh_h2[2][H2_];

    // ---- per-lane weight registers ----
    // layer 1: lane owns gate rows  ga = lane (i_u for lane<32 / f_u for lane>=32, u=lane&31)
    //                               gb = 64+lane (g_u / o_u)
    const int ga = lane;
    const int gb = 64 + lane;
    float w1a[H1_], w1b[H1_];
    #pragma unroll
    for (int k = 0; k < H1_; ++k) {
        w1a[k] = W_hh1[ga * H1_ + k];
        w1b[k] = W_hh1[gb * H1_ + k];
    }
    const float wxa = W_ih1[ga];              // N_IN == 1
    const float wxb = W_ih1[gb];
    const float ba  = b_ih1[ga] + b_hh1[ga];
    const float bb  = b_ih1[gb] + b_hh1[gb];

    // layer 2: lane owns gate row `lane` of the 64 (i:0-15, f:16-31, g:32-47, o:48-63)
    float w2a[H1_];
    #pragma unroll
    for (int k = 0; k < H1_; ++k) w2a[k] = W_ih2[lane * H1_ + k];
    float w2b[H2_];
    #pragma unroll
    for (int k = 0; k < H2_; ++k) w2b[k] = W_hh2[lane * H2_ + k];
    const float b2 = b_ih2[lane] + b_hh2[lane];

    const int   u2   = lane & 15;
    const float wout = W_out[u2];
    const float bout = b_out[0];

    // branchless activation-select constants:  act = a + b / (1 + exp(m*x))
    //   sigmoid: m=-1, a=0, b=1        tanh: m=2, a=1, b=-2
    const bool  low = (lane < 32);
    const float m1 = low ? 2.0f : -1.0f;   // b-side of layer1: tanh(g) | sigmoid(o)
    const float a1 = low ? 1.0f :  0.0f;
    const float b1 = low ? -2.0f : 1.0f;
    const int   gt = lane >> 4;
    const float m2  = (gt == 2) ? 2.0f : -1.0f;  // layer2: g-gate is tanh
    const float a2  = (gt == 2) ? 1.0f :  0.0f;
    const float b2c = (gt == 2) ? -2.0f : 1.0f;

    // ---- state ----
    float h1r[H1_];
    #pragma unroll
    for (int k = 0; k < H1_; ++k) h1r[k] = 0.0f;
    float h2r[H2_];
    #pragma unroll
    for (int k = 0; k < H2_; ++k) h2r[k] = 0.0f;
    float c1 = 0.0f;   // valid in high lanes: unit (lane-32)
    float c2 = 0.0f;   // replicated 4x: unit u2

    if (lane < H2_) { sh_h2[0][lane] = 0.0f; sh_h2[1][lane] = 0.0f; }
    __syncthreads();

    const float* __restrict__ xrow = x   + (size_t)row * T_;
    float*       __restrict__ orow = out + (size_t)row * T_;

    #pragma unroll 1
    for (int t = 0; t < T_; ++t) {
        const float xt = xrow[t];

        // ---- layer 1 gate dots (all register operands) ----
        float acca = __builtin_fmaf(wxa, xt, ba);
        float accb = __builtin_fmaf(wxb, xt, bb);
        #pragma unroll
        for (int k = 0; k < H1_; ++k) {
            acca = __builtin_fmaf(w1a[k], h1r[k], acca);
            accb = __builtin_fmaf(w1b[k], h1r[k], accb);
        }

        // low lane u: sa=sig(i_u), sb=tanh(g_u) ; high lane u: sa=sig(f_u), sb=sig(o_u)
        const float sa = 1.0f / (1.0f + __expf(-acca));
        const float sb = a1 + b1 / (1.0f + __expf(m1 * accb));
        const float pv = __shfl_xor(sa * sb, 32);        // high lanes receive p = sig(i)*tanh(g)
        c1 = __builtin_fmaf(sa, c1, pv);                 // high: sig(f)*c1 + p  (low: benign junk)
        const float tc1 = 1.0f - 2.0f / (1.0f + __expf(2.0f * c1));
        const float h1new = sb * tc1;                    // high: sig(o)*tanh(c1)

        if (lane >= 32) sh_h1[lane - 32] = h1new;
        __syncthreads();   // also orders last iter's sh_h2 write (single wave: cheap)

        // refresh replicated h1 (h1_t) and h2 (h2_{t-1}) registers, vector LDS reads
        {
            const float4* p4 = reinterpret_cast<const float4*>(sh_h1);
            #pragma unroll
            for (int q = 0; q < H1_ / 4; ++q) {
                const float4 v = p4[q];
                h1r[4*q+0] = v.x; h1r[4*q+1] = v.y; h1r[4*q+2] = v.z; h1r[4*q+3] = v.w;
            }
            const float4* q4 = reinterpret_cast<const float4*>(sh_h2[(t & 1) ^ 1]);
            #pragma unroll
            for (int q = 0; q < H2_ / 4; ++q) {
                const float4 v = q4[q];
                h2r[4*q+0] = v.x; h2r[4*q+1] = v.y; h2r[4*q+2] = v.z; h2r[4*q+3] = v.w;
            }
        }

        // ---- layer 2 gate dot (4 independent FMA chains) ----
        float e0 = b2, e1 = 0.0f, e2 = 0.0f, e3 = 0.0f;
        #pragma unroll
        for (int k = 0; k < H1_; k += 4) {
            e0 = __builtin_fmaf(w2a[k+0], h1r[k+0], e0);
            e1 = __builtin_fmaf(w2a[k+1], h1r[k+1], e1);
            e2 = __builtin_fmaf(w2a[k+2], h1r[k+2], e2);
            e3 = __builtin_fmaf(w2a[k+3], h1r[k+3], e3);
        }
        #pragma unroll
        for (int k = 0; k < H2_; k += 4) {
            e0 = __builtin_fmaf(w2b[k+0], h2r[k+0], e0);
            e1 = __builtin_fmaf(w2b[k+1], h2r[k+1], e1);
            e2 = __builtin_fmaf(w2b[k+2], h2r[k+2], e2);
            e3 = __builtin_fmaf(w2b[k+3], h2r[k+3], e3);
        }
        const float d2 = (e0 + e1) + (e2 + e3);

        const float s2 = a2 + b2c / (1.0f + __expf(m2 * d2));  // activated gate `lane`
        const float iv = __shfl(s2, u2);
        const float fv = __shfl(s2, u2 + 16);
        const float gv = __shfl(s2, u2 + 32);
        const float ov = __shfl(s2, u2 + 48);

        c2 = __builtin_fmaf(fv, c2, iv * gv);
        const float tc2 = 1.0f - 2.0f / (1.0f + __expf(2.0f * c2));
        const float h2v = ov * tc2;                      // h2_t[u2], replicated x4

        // y = h2_t . W_out + b_out  (xor-reduce within 16-lane groups)
        float part = wout * h2v;
        part += __shfl_xor(part, 1);
        part += __shfl_xor(part, 2);
        part += __shfl_xor(part, 4);
        part += __shfl_xor(part, 8);
        if (lane == 0) orow[t] = part + bout;

        if (lane < H2_) sh_h2[t & 1][lane] = h2v;        // consumed after next iter's barrier
    }
}

extern "C" void kernel_launch(void* const* d_in, const int* in_sizes, int n_in,
                              void* d_out, int out_size, void* d_ws, size_t ws_size,
                              hipStream_t stream) {
    const float* xp     = (const float*)d_in[0];
    const float* W_ih1  = (const float*)d_in[1];
    const float* W_hh1  = (const float*)d_in[2];
    const float* b_ih1  = (const float*)d_in[3];
    const float* b_hh1  = (const float*)d_in[4];
    const float* W_ih2  = (const float*)d_in[5];
    const float* W_hh2  = (const float*)d_in[6];
    const float* b_ih2  = (const float*)d_in[7];
    const float* b_hh2  = (const float*)d_in[8];
    const float* W_out  = (const float*)d_in[9];
    const float* b_out  = (const float*)d_in[10];
    float* out = (float*)d_out;

    dim3 grid(B_);
    dim3 block(64);
    lstm_deep_kernel<<<grid, block, 0, stream>>>(
        xp, W_ih1, W_hh1, b_ih1, b_hh1, W_ih2, W_hh2, b_ih2, b_hh2, W_out, b_out, out);
}

// Round 2
// 2943.703 us; speedup vs baseline: 1.2482x; 1.2482x over previous
//
#include <hip/hip_runtime.h>

#define B_  4096
#define T_  2048
#define H1_ 32
#define H2_ 16

#define LOG2E     1.44269504088896340736f
#define TWOLOG2E  2.88539008177792681472f

// Activations in exp2 domain. Gate weights/biases pre-scaled by log2(e), so:
//   sigmoid(x) = rcp(1 + exp2(-x'))
//   tanh(g)    = 1 - 2*rcp(1 + exp2(2*g'))
// Cell states stay in linear units: tanh(c) = 1 - 2*rcp(1 + exp2(2*log2e*c)).
// v_rcp_f32 / v_exp_f32 are ~1 ulp; absmax budget has 21x headroom vs R1.

__global__ __launch_bounds__(64, 2) void lstm_deep_kernel(
    const float* __restrict__ x,
    const float* __restrict__ W_ih1,
    const float* __restrict__ W_hh1,
    const float* __restrict__ b_ih1,
    const float* __restrict__ b_hh1,
    const float* __restrict__ W_ih2,
    const float* __restrict__ W_hh2,
    const float* __restrict__ b_ih2,
    const float* __restrict__ b_hh2,
    const float* __restrict__ W_out,
    const float* __restrict__ b_out,
    float* __restrict__ out)
{
    const int lane = threadIdx.x;   // 0..63, single wave per block
    const int row  = blockIdx.x;    // batch row

    __shared__ __align__(16) float sh_h1[H1_];
    __shared__ __align__(16) float sh_h2[2][H2_];

    // ---- per-lane weight registers (pre-scaled by log2e) ----
    // layer 1: lane owns gate rows ga = lane (i_u / f_u, u=lane&31), gb = 64+lane (g_u / o_u)
    const int ga = lane;
    const int gb = 64 + lane;
    float w1a[H1_], w1b[H1_];
    #pragma unroll
    for (int k = 0; k < H1_; ++k) {
        w1a[k] = W_hh1[ga * H1_ + k] * LOG2E;
        w1b[k] = W_hh1[gb * H1_ + k] * LOG2E;
    }
    const float wxa = W_ih1[ga] * LOG2E;              // N_IN == 1
    const float wxb = W_ih1[gb] * LOG2E;
    const float ba  = (b_ih1[ga] + b_hh1[ga]) * LOG2E;
    const float bb  = (b_ih1[gb] + b_hh1[gb]) * LOG2E;

    // layer 2: lane owns gate row `lane` (i:0-15, f:16-31, g:32-47, o:48-63)
    float w2a[H1_];
    #pragma unroll
    for (int k = 0; k < H1_; ++k) w2a[k] = W_ih2[lane * H1_ + k] * LOG2E;
    float w2b[H2_];
    #pragma unroll
    for (int k = 0; k < H2_; ++k) w2b[k] = W_hh2[lane * H2_ + k] * LOG2E;
    const float b2 = (b_ih2[lane] + b_hh2[lane]) * LOG2E;

    const int   u2   = lane & 15;
    const float wout = W_out[u2];
    const float bout = b_out[0];

    // branchless activation-select constants:  act = a + b * rcp(1 + exp2(m*x'))
    //   sigmoid: m=-1, a=0, b=1        tanh: m=2, a=1, b=-2
    const bool  low = (lane < 32);
    const float m1 = low ? 2.0f : -1.0f;   // b-side of layer1: tanh(g) | sigmoid(o)
    const float a1 = low ? 1.0f :  0.0f;
    const float b1 = low ? -2.0f : 1.0f;
    const int   gt = lane >> 4;
    const float m2  = (gt == 2) ? 2.0f : -1.0f;  // layer2: g-gate is tanh
    const float a2  = (gt == 2) ? 1.0f :  0.0f;
    const float b2c = (gt == 2) ? -2.0f : 1.0f;

    // ---- state ----
    float h1r[H1_];
    #pragma unroll
    for (int k = 0; k < H1_; ++k) h1r[k] = 0.0f;
    float h2r[H2_];
    #pragma unroll
    for (int k = 0; k < H2_; ++k) h2r[k] = 0.0f;
    float c1 = 0.0f;   // valid in high lanes: unit (lane-32)
    float c2 = 0.0f;   // replicated 4x: unit u2

    if (lane < H2_) { sh_h2[0][lane] = 0.0f; sh_h2[1][lane] = 0.0f; }
    __syncthreads();

    const float*  __restrict__ xrow = x   + (size_t)row * T_;
    const float4* __restrict__ x4   = reinterpret_cast<const float4*>(xrow);
    float*        __restrict__ orow = out + (size_t)row * T_;

    auto step = [&](float xt, int par, int t) {
        // ---- layer 1 gate dots (all register operands) ----
        float acca = __builtin_fmaf(wxa, xt, ba);
        float accb = __builtin_fmaf(wxb, xt, bb);
        #pragma unroll
        for (int k = 0; k < H1_; ++k) {
            acca = __builtin_fmaf(w1a[k], h1r[k], acca);
            accb = __builtin_fmaf(w1b[k], h1r[k], accb);
        }

        // low lane u: sa=sig(i_u), sb=tanh(g_u) ; high lane u: sa=sig(f_u), sb=sig(o_u)
        const float sa = __builtin_amdgcn_rcpf(1.0f + __builtin_amdgcn_exp2f(-acca));
        const float sb = __builtin_fmaf(
            b1, __builtin_amdgcn_rcpf(1.0f + __builtin_amdgcn_exp2f(m1 * accb)), a1);
        const float pv = __shfl_xor(sa * sb, 32);  // high lanes receive p = sig(i)*tanh(g)
        c1 = __builtin_fmaf(sa, c1, pv);           // high: sig(f)*c1 + p  (low: benign junk)
        const float tc1 = __builtin_fmaf(
            -2.0f, __builtin_amdgcn_rcpf(1.0f + __builtin_amdgcn_exp2f(TWOLOG2E * c1)), 1.0f);
        const float h1new = sb * tc1;              // high: sig(o)*tanh(c1)

        if (lane >= 32) sh_h1[lane - 32] = h1new;
        __syncthreads();   // also orders last iter's sh_h2 write (single wave: cheap)

        // refresh replicated h1 (h1_t) and h2 (h2_{t-1}) registers, vector LDS reads
        {
            const float4* p4 = reinterpret_cast<const float4*>(sh_h1);
            #pragma unroll
            for (int q = 0; q < H1_ / 4; ++q) {
                const float4 v = p4[q];
                h1r[4*q+0] = v.x; h1r[4*q+1] = v.y; h1r[4*q+2] = v.z; h1r[4*q+3] = v.w;
            }
            const float4* q4 = reinterpret_cast<const float4*>(sh_h2[par ^ 1]);
            #pragma unroll
            for (int q = 0; q < H2_ / 4; ++q) {
                const float4 v = q4[q];
                h2r[4*q+0] = v.x; h2r[4*q+1] = v.y; h2r[4*q+2] = v.z; h2r[4*q+3] = v.w;
            }
        }

        // ---- layer 2 gate dot (4 independent FMA chains) ----
        float e0 = b2, e1 = 0.0f, e2 = 0.0f, e3 = 0.0f;
        #pragma unroll
        for (int k = 0; k < H1_; k += 4) {
            e0 = __builtin_fmaf(w2a[k+0], h1r[k+0], e0);
            e1 = __builtin_fmaf(w2a[k+1], h1r[k+1], e1);
            e2 = __builtin_fmaf(w2a[k+2], h1r[k+2], e2);
            e3 = __builtin_fmaf(w2a[k+3], h1r[k+3], e3);
        }
        #pragma unroll
        for (int k = 0; k < H2_; k += 4) {
            e0 = __builtin_fmaf(w2b[k+0], h2r[k+0], e0);
            e1 = __builtin_fmaf(w2b[k+1], h2r[k+1], e1);
            e2 = __builtin_fmaf(w2b[k+2], h2r[k+2], e2);
            e3 = __builtin_fmaf(w2b[k+3], h2r[k+3], e3);
        }
        const float d2 = (e0 + e1) + (e2 + e3);

        const float s2 = __builtin_fmaf(
            b2c, __builtin_amdgcn_rcpf(1.0f + __builtin_amdgcn_exp2f(m2 * d2)), a2);
        const float iv = __shfl(s2, u2);
        const float fv = __shfl(s2, u2 + 16);
        const float gv = __shfl(s2, u2 + 32);
        const float ov = __shfl(s2, u2 + 48);

        c2 = __builtin_fmaf(fv, c2, iv * gv);
        const float tc2 = __builtin_fmaf(
            -2.0f, __builtin_amdgcn_rcpf(1.0f + __builtin_amdgcn_exp2f(TWOLOG2E * c2)), 1.0f);
        const float h2v = ov * tc2;                // h2_t[u2], replicated x4

        // y = h2_t . W_out + b_out  (xor-reduce within 16-lane groups)
        float part = wout * h2v;
        part += __shfl_xor(part, 1);
        part += __shfl_xor(part, 2);
        part += __shfl_xor(part, 4);
        part += __shfl_xor(part, 8);
        if (lane == 0) orow[t] = part + bout;

        if (lane < H2_) sh_h2[par][lane] = h2v;    // consumed after next iter's barrier
    };

    #pragma unroll 1
    for (int t4 = 0; t4 < T_ / 4; ++t4) {
        const float4 xv = x4[t4];
        const int t = t4 * 4;
        step(xv.x, 0, t + 0);
        step(xv.y, 1, t + 1);
        step(xv.z, 0, t + 2);
        step(xv.w, 1, t + 3);
    }
}

extern "C" void kernel_launch(void* const* d_in, const int* in_sizes, int n_in,
                              void* d_out, int out_size, void* d_ws, size_t ws_size,
                              hipStream_t stream) {
    const float* xp     = (const float*)d_in[0];
    const float* W_ih1  = (const float*)d_in[1];
    const float* W_hh1  = (const float*)d_in[2];
    const float* b_ih1  = (const float*)d_in[3];
    const float* b_hh1  = (const float*)d_in[4];
    const float* W_ih2  = (const float*)d_in[5];
    const float* W_hh2  = (const float*)d_in[6];
    const float* b_ih2  = (const float*)d_in[7];
    const float* b_hh2  = (const float*)d_in[8];
    const float* W_out  = (const float*)d_in[9];
    const float* b_out  = (const float*)d_in[10];
    float* out = (float*)d_out;

    dim3 grid(B_);
    dim3 block(64);
    lstm_deep_kernel<<<grid, block, 0, stream>>>(
        xp, W_ih1, W_hh1, b_ih1, b_hh1, W_ih2, W_hh2, b_ih2, b_hh2, W_out, b_out, out);
}